// Round 5
// baseline (171.402 us; speedup 1.0000x reference)
//
#include <hip/hip_runtime.h>
#include <math.h>

#define HH 480
#define WW 640
#define HW (HH*WW)

// ---------------- K1: horizontal resample + p maps ----------------

__device__ __forceinline__ float sample1(const float* __restrict__ row, float x) {
    float x0 = floorf(x);
    float w1 = x - x0;
    int xi = (int)x0;
    float v0 = (xi >= 0 && xi < WW) ? row[xi] : 0.f;
    float v1 = (xi + 1 >= 0 && xi + 1 < WW) ? row[xi + 1] : 0.f;
    return v0 * (1.f - w1) + v1 * w1;
}

__global__ __launch_bounds__(256) void k_resample(
    const float* __restrict__ left, const float* __restrict__ right,
    const float* __restrict__ dispL, const float* __restrict__ dispR,
    float* __restrict__ rir, float* __restrict__ ril,
    float* __restrict__ pL, float* __restrict__ pR)
{
    int idx = blockIdx.x * blockDim.x + threadIdx.x;
    if (idx >= HW) return;
    int h = idx / WW;
    int w = idx - h * WW;
    float dL = dispL[idx];
    float dR = dispR[idx];
    float xl = (float)w - dL;   // sample right view at j - dispL
    float xr = (float)w + dR;   // sample left view  at j + dispR
    #pragma unroll
    for (int c = 0; c < 3; ++c) {
        rir[c*HW + idx] = sample1(right + c*HW + h*WW, xl);
        ril[c*HW + idx] = sample1(left  + c*HW + h*WW, xr);
    }
    float rdr = sample1(dispR + h*WW, xl);
    float rdl = sample1(dispL + h*WW, xr);
    pL[idx] = __expf(-0.6931f * fabsf(dL - rdr));
    pR[idx] = __expf(-0.6931f * fabsf(dR - rdl));
}

// ---------------- K2: 9x9 LCN (separable) + cost, one side per blockIdx.z ----------------
// block 32x8, tile rows 16 (8+2*4), cols 40 (32+2*4)

__global__ __launch_bounds__(256) void k_lcncost(
    const float* __restrict__ left, const float* __restrict__ right,
    const float* __restrict__ rir, const float* __restrict__ ril,
    float* __restrict__ costL, float* __restrict__ costR)
{
    __shared__ float raw[6][16][40];   // 15360 B
    __shared__ float hs [6][16][32];   // 12288 B
    __shared__ float hs2[6][16][32];   // 12288 B
    int tx = threadIdx.x, ty = threadIdx.y;
    int tid = ty * 32 + tx;
    int gx0 = blockIdx.x * 32, gy0 = blockIdx.y * 8;
    const float* __restrict__ imgA = blockIdx.z ? right : left;   // real image (std source)
    const float* __restrict__ imgB = blockIdx.z ? ril   : rir;    // reconstruction
    float* __restrict__ out = blockIdx.z ? costR : costL;

    for (int e = tid; e < 6*16*40; e += 256) {
        int a   = e / (16*40);
        int rem = e - a * (16*40);
        int r   = rem / 40;
        int x   = rem - r * 40;
        int gy = gy0 + r - 4, gx = gx0 + x - 4;
        float v = 0.f;
        if ((unsigned)gy < (unsigned)HH && (unsigned)gx < (unsigned)WW) {
            const float* s = (a < 3) ? imgA : imgB;
            int ch = (a < 3) ? a : a - 3;
            v = s[ch*HW + gy*WW + gx];
        }
        ((float*)raw)[e] = v;
    }
    __syncthreads();

    for (int e = tid; e < 6*16*32; e += 256) {
        int a   = e / (16*32);
        int rem = e - a * (16*32);
        int r   = rem / 32;
        int x   = rem - r * 32;
        float s = 0.f, s2 = 0.f;
        #pragma unroll
        for (int dx = 0; dx < 9; ++dx) {
            float v = raw[a][r][x + dx];
            s += v;
            s2 = fmaf(v, v, s2);
        }
        ((float*)hs)[e]  = s;
        ((float*)hs2)[e] = s2;
    }
    __syncthreads();

    int idx = (gy0 + ty) * WW + gx0 + tx;
    #pragma unroll
    for (int c = 0; c < 3; ++c) {
        float SA = 0.f, SA2 = 0.f, SB = 0.f, SB2 = 0.f;
        #pragma unroll
        for (int dy = 0; dy < 9; ++dy) {
            SA  += hs [c][ty + dy][tx];
            SA2 += hs2[c][ty + dy][tx];
            SB  += hs [3 + c][ty + dy][tx];
            SB2 += hs2[3 + c][ty + dy][tx];
        }
        float meanA = SA * (1.f/81.f);
        float stdA  = sqrtf(fmaxf(SA2 * (1.f/81.f) - meanA * meanA, 0.f)) * (81.f/80.f);
        float lcnA  = (raw[c][ty + 4][tx + 4] - meanA) / (stdA + 1e-5f);
        float meanB = SB * (1.f/81.f);
        float stdB  = sqrtf(fmaxf(SB2 * (1.f/81.f) - meanB * meanB, 0.f)) * (81.f/80.f);
        float lcnB  = (raw[3 + c][ty + 4][tx + 4] - meanB) / (stdB + 1e-5f);
        out[c*HW + idx] = fabsf((lcnA - lcnB) * stdA);
    }
}

// ---------------- K3: 12x12 ASW + losses + reduction ----------------
// block (32,4,3) = 384 threads = 6 waves, output region 32x8 per block.
// Thread (tx,ty,c): channel c of 2 outputs (gx0+tx, gy0+2ty+i), i=0,1.
// Tile float2: .x = guide f32, .y = packed bf16 pair (costL | costR<<16).
// Tap rows kap = i + dy' (dy' 0..11): kap 0 -> i=0; 1..11 -> both; 12 -> i=1.

#define T3H 19
#define T3W 43

__global__ __launch_bounds__(384) void k_asw_reduce(
    const float* __restrict__ left, const float* __restrict__ right,
    const float* __restrict__ rir, const float* __restrict__ ril,
    const float* __restrict__ costL, const float* __restrict__ costR,
    const float* __restrict__ pL, const float* __restrict__ pR,
    float* __restrict__ acc)
{
    __shared__ float2 tile[3][T3H][T3W];   // 19608 B
    __shared__ float red[6][6];
    int tx = threadIdx.x, ty = threadIdx.y, c = threadIdx.z;
    int tid = tx + 32 * ty + 128 * c;
    int gx0 = blockIdx.x * 32, gy0 = blockIdx.y * 8;

    for (int e = tid; e < 3 * T3H * T3W; e += 384) {
        int cc  = e / (T3H * T3W);
        int rem = e - cc * (T3H * T3W);
        int r   = rem / T3W;
        int x   = rem - r * T3W;
        int gy = gy0 + r - 6, gx = gx0 + x - 6;
        float2 v = make_float2(0.f, 0.f);
        if ((unsigned)gy < (unsigned)HH && (unsigned)gx < (unsigned)WW) {
            int o = cc*HW + gy*WW + gx;
            v.x = left[o];
            unsigned ul = __float_as_uint(costL[o]);
            ul = (ul + 0x7fffu + ((ul >> 16) & 1u)) >> 16;          // bf16 RNE, low half
            unsigned ur = __float_as_uint(costR[o]);
            ur = (ur + 0x7fffu + ((ur >> 16) & 1u)) & 0xffff0000u;  // bf16 RNE, high half
            v.y = __uint_as_float(ul | ur);
        }
        tile[cc][r][x] = v;
    }
    __syncthreads();

    int ty2 = 2 * ty;
    float g[2];
    g[0] = tile[c][ty2 + 6][tx + 6].x;
    g[1] = tile[c][ty2 + 7][tx + 6].x;

    float wg[2] = {0.f, 0.f}, aL[2] = {0.f, 0.f}, aR[2] = {0.f, 0.f};

    auto taprow = [&](int kap, bool do0, bool do1) {
        int r = ty2 + kap;
        #pragma unroll
        for (int dx = 0; dx < 12; ++dx) {
            float2 v = tile[c][r][tx + dx];
            unsigned pk = __float_as_uint(v.y);
            float cl = __uint_as_float(pk << 16);
            float cr = __uint_as_float(pk & 0xffff0000u);
            if (do0) {
                float t = __expf(-0.5f * fabsf(g[0] - v.x));
                wg[0] += t;
                aL[0] = fmaf(t, cl, aL[0]);
                aR[0] = fmaf(t, cr, aR[0]);
            }
            if (do1) {
                float t = __expf(-0.5f * fabsf(g[1] - v.x));
                wg[1] += t;
                aL[1] = fmaf(t, cl, aL[1]);
                aR[1] = fmaf(t, cr, aR[1]);
            }
        }
    };

    taprow(0, true, false);
    for (int kap = 1; kap <= 11; ++kap)
        taprow(kap, true, true);
    taprow(12, false, true);

    float vals[6] = {0.f, 0.f, 0.f, 0.f, 0.f, 0.f};
    #pragma unroll
    for (int i = 0; i < 2; ++i) {
        int idx = (gy0 + ty2 + i) * WW + gx0 + tx;
        float aswL   = aL[i] / wg[i];
        float photoL = fabsf(g[i] - rir[c*HW + idx]);
        float sLp = 0.5f * photoL + 0.5f * aswL;
        float aswR   = aR[i] / wg[i];
        float photoR = fabsf(right[c*HW + idx] - ril[c*HW + idx]);
        float sRp = 0.5f * photoR + 0.5f * aswR;
        float pl = pL[idx], pr = pR[idx];
        float mL = (pl > 0.5f) ? 1.f : 0.f;
        float mR = (pr > 0.5f) ? 1.f : 0.f;
        vals[0] += sLp * mL;
        vals[2] += sRp * mR;
        if (c == 0) {   // per-pixel terms counted once
            vals[1] += mL;
            vals[3] += mR;
            vals[4] += log1pf(__expf(1.f - 2.f * pl));
            vals[5] += log1pf(__expf(1.f - 2.f * pr));
        }
    }

    int lane = tid & 63, wave = tid >> 6;
    #pragma unroll
    for (int k = 0; k < 6; ++k) {
        float v = vals[k];
        #pragma unroll
        for (int off = 32; off > 0; off >>= 1) v += __shfl_down(v, off);
        if (lane == 0) red[wave][k] = v;
    }
    __syncthreads();
    if (tid == 0) {
        #pragma unroll
        for (int k = 0; k < 6; ++k) {
            float s = red[0][k] + red[1][k] + red[2][k] + red[3][k] + red[4][k] + red[5][k];
            atomicAdd(&acc[k], s);
        }
    }
}

// ---------------- K4: finalize ----------------

__global__ void k_final(const float* __restrict__ acc, const float* __restrict__ weight,
                        float* __restrict__ out)
{
    float S1 = acc[0], M1 = acc[1], S2 = acc[2], M2 = acc[3], C1 = acc[4], C2 = acc[5];
    float loss_valid = S1 / (3.f * M1 + 1e-6f) + S2 / (3.f * M2 + 1e-6f);
    float loss_invalid = (C1 + C2) * (1.f / (float)HW);
    out[0] = weight[0] * (0.9f * loss_valid + 0.1f * loss_invalid);
}

// ---------------- launch ----------------

extern "C" void kernel_launch(void* const* d_in, const int* in_sizes, int n_in,
                              void* d_out, int out_size, void* d_ws, size_t ws_size,
                              hipStream_t stream)
{
    const float* left  = (const float*)d_in[0];
    const float* right = (const float*)d_in[1];
    const float* dispL = (const float*)d_in[2];
    const float* dispR = (const float*)d_in[3];
    // d_in[4] = dispmap_gt (unused), d_in[5] = brk (unused)
    const float* weight = (const float*)d_in[6];

    float* ws    = (float*)d_ws;
    float* acc   = ws;              // 8 floats (6 used)
    float* rir   = ws + 8;          // 3*HW
    float* ril   = rir + 3*HW;      // 3*HW
    float* pL    = ril + 3*HW;      // HW
    float* pR    = pL + HW;         // HW
    float* costL = pR + HW;         // 3*HW
    float* costR = costL + 3*HW;    // 3*HW

    hipMemsetAsync(acc, 0, 8 * sizeof(float), stream);

    k_resample<<<(HW + 255) / 256, 256, 0, stream>>>(left, right, dispL, dispR, rir, ril, pL, pR);

    dim3 blk2(32, 8);
    dim3 grd2(WW / 32, HH / 8, 2);
    k_lcncost<<<grd2, blk2, 0, stream>>>(left, right, rir, ril, costL, costR);

    dim3 blk3(32, 4, 3);
    dim3 grd3(WW / 32, HH / 8);
    k_asw_reduce<<<grd3, blk3, 0, stream>>>(left, right, rir, ril, costL, costR, pL, pR, acc);

    k_final<<<1, 1, 0, stream>>>(acc, weight, (float*)d_out);
}

// Round 6
// 149.693 us; speedup vs baseline: 1.1450x; 1.1450x over previous
//
#include <hip/hip_runtime.h>
#include <math.h>

#define HH 480
#define WW 640
#define HW (HH*WW)

// ---------------- K1: horizontal resample + p maps ----------------

__device__ __forceinline__ float sample1(const float* __restrict__ row, float x) {
    float x0 = floorf(x);
    float w1 = x - x0;
    int xi = (int)x0;
    float v0 = (xi >= 0 && xi < WW) ? row[xi] : 0.f;
    float v1 = (xi + 1 >= 0 && xi + 1 < WW) ? row[xi + 1] : 0.f;
    return v0 * (1.f - w1) + v1 * w1;
}

__global__ __launch_bounds__(256) void k_resample(
    const float* __restrict__ left, const float* __restrict__ right,
    const float* __restrict__ dispL, const float* __restrict__ dispR,
    float* __restrict__ rir, float* __restrict__ ril,
    float* __restrict__ pL, float* __restrict__ pR)
{
    int idx = blockIdx.x * blockDim.x + threadIdx.x;
    if (idx >= HW) return;
    int h = idx / WW;
    int w = idx - h * WW;
    float dL = dispL[idx];
    float dR = dispR[idx];
    float xl = (float)w - dL;   // sample right view at j - dispL
    float xr = (float)w + dR;   // sample left view  at j + dispR
    #pragma unroll
    for (int c = 0; c < 3; ++c) {
        rir[c*HW + idx] = sample1(right + c*HW + h*WW, xl);
        ril[c*HW + idx] = sample1(left  + c*HW + h*WW, xr);
    }
    float rdr = sample1(dispR + h*WW, xl);
    float rdl = sample1(dispL + h*WW, xr);
    pL[idx] = __expf(-0.6931f * fabsf(dL - rdr));
    pR[idx] = __expf(-0.6931f * fabsf(dR - rdl));
}

// ---------------- K2: 9x9 LCN (separable) + cost, one side per blockIdx.z ----------------
// block 32x8, tile rows 16 (8+2*4), cols 40 (32+2*4)

__global__ __launch_bounds__(256) void k_lcncost(
    const float* __restrict__ left, const float* __restrict__ right,
    const float* __restrict__ rir, const float* __restrict__ ril,
    float* __restrict__ costL, float* __restrict__ costR)
{
    __shared__ float raw[6][16][40];   // 15360 B
    __shared__ float hs [6][16][32];   // 12288 B
    __shared__ float hs2[6][16][32];   // 12288 B
    int tx = threadIdx.x, ty = threadIdx.y;
    int tid = ty * 32 + tx;
    int gx0 = blockIdx.x * 32, gy0 = blockIdx.y * 8;
    const float* __restrict__ imgA = blockIdx.z ? right : left;   // real image (std source)
    const float* __restrict__ imgB = blockIdx.z ? ril   : rir;    // reconstruction
    float* __restrict__ out = blockIdx.z ? costR : costL;

    for (int e = tid; e < 6*16*40; e += 256) {
        int a   = e / (16*40);
        int rem = e - a * (16*40);
        int r   = rem / 40;
        int x   = rem - r * 40;
        int gy = gy0 + r - 4, gx = gx0 + x - 4;
        float v = 0.f;
        if ((unsigned)gy < (unsigned)HH && (unsigned)gx < (unsigned)WW) {
            const float* s = (a < 3) ? imgA : imgB;
            int ch = (a < 3) ? a : a - 3;
            v = s[ch*HW + gy*WW + gx];
        }
        ((float*)raw)[e] = v;
    }
    __syncthreads();

    for (int e = tid; e < 6*16*32; e += 256) {
        int a   = e / (16*32);
        int rem = e - a * (16*32);
        int r   = rem / 32;
        int x   = rem - r * 32;
        float s = 0.f, s2 = 0.f;
        #pragma unroll
        for (int dx = 0; dx < 9; ++dx) {
            float v = raw[a][r][x + dx];
            s += v;
            s2 = fmaf(v, v, s2);
        }
        ((float*)hs)[e]  = s;
        ((float*)hs2)[e] = s2;
    }
    __syncthreads();

    int idx = (gy0 + ty) * WW + gx0 + tx;
    #pragma unroll
    for (int c = 0; c < 3; ++c) {
        float SA = 0.f, SA2 = 0.f, SB = 0.f, SB2 = 0.f;
        #pragma unroll
        for (int dy = 0; dy < 9; ++dy) {
            SA  += hs [c][ty + dy][tx];
            SA2 += hs2[c][ty + dy][tx];
            SB  += hs [3 + c][ty + dy][tx];
            SB2 += hs2[3 + c][ty + dy][tx];
        }
        float meanA = SA * (1.f/81.f);
        float stdA  = sqrtf(fmaxf(SA2 * (1.f/81.f) - meanA * meanA, 0.f)) * (81.f/80.f);
        float lcnA  = (raw[c][ty + 4][tx + 4] - meanA) / (stdA + 1e-5f);
        float meanB = SB * (1.f/81.f);
        float stdB  = sqrtf(fmaxf(SB2 * (1.f/81.f) - meanB * meanB, 0.f)) * (81.f/80.f);
        float lcnB  = (raw[3 + c][ty + 4][tx + 4] - meanB) / (stdB + 1e-5f);
        out[c*HW + idx] = fabsf((lcnA - lcnB) * stdA);
    }
}

// ---------------- K3: 12x12 ASW + losses + reduction (exp-free taps) ----------------
// block (32,4,3) = 384 threads = 6 waves; thread (tx,ty,c): channel c of 4 outputs
// (gx0+tx, gy0+4ty+i), i=0..3; region 32x16/block.
// Tile uint2: .x = bf16(Ep)|bf16(Em)<<16 with Ep=exp(g/2), Em=exp(-g/2);
//             .y = bf16(costL)|bf16(costR)<<16.
// OOB halo encodes g=0 => Ep=Em=1.0 (NOT zero), costs=0, matching zero-pad reference.
// Per tap: t = exp(-|g_c-g_q|/2) = min(Em_c*Ep_q, Ep_c*Em_q)  — no per-tap exp.

#define T3H 27
#define T3W 43

__device__ __forceinline__ unsigned bf16rne(float f) {
    unsigned u = __float_as_uint(f);
    return (u + 0x7fffu + ((u >> 16) & 1u)) >> 16;
}

__global__ __launch_bounds__(384) void k_asw_reduce(
    const float* __restrict__ left, const float* __restrict__ right,
    const float* __restrict__ rir, const float* __restrict__ ril,
    const float* __restrict__ costL, const float* __restrict__ costR,
    const float* __restrict__ pL, const float* __restrict__ pR,
    float* __restrict__ acc)
{
    __shared__ uint2 tile[3][T3H][T3W];   // 27864 B
    __shared__ float red[6][6];
    int tx = threadIdx.x, ty = threadIdx.y, c = threadIdx.z;
    int tid = tx + 32 * ty + 128 * c;
    int gx0 = blockIdx.x * 32, gy0 = blockIdx.y * 16;

    for (int e = tid; e < 3 * T3H * T3W; e += 384) {
        int cc  = e / (T3H * T3W);
        int rem = e - cc * (T3H * T3W);
        int r   = rem / T3W;
        int x   = rem - r * T3W;
        int gy = gy0 + r - 6, gx = gx0 + x - 6;
        uint2 v = make_uint2(0x3f803f80u, 0u);   // g=0: Ep=Em=1.0, costs 0
        if ((unsigned)gy < (unsigned)HH && (unsigned)gx < (unsigned)WW) {
            int o = cc*HW + gy*WW + gx;
            float g = left[o];
            float ep = __expf(0.5f * g);
            float em = __expf(-0.5f * g);
            v.x = bf16rne(ep) | (bf16rne(em) << 16);
            v.y = bf16rne(costL[o]) | (bf16rne(costR[o]) << 16);
        }
        tile[cc][r][x] = v;
    }
    __syncthreads();

    int ty4 = 4 * ty;
    float epc[4], emc[4];
    #pragma unroll
    for (int i = 0; i < 4; ++i) {
        unsigned vc = tile[c][ty4 + i + 6][tx + 6].x;
        epc[i] = __uint_as_float(vc << 16);
        emc[i] = __uint_as_float(vc & 0xffff0000u);
    }

    float wg[4] = {0.f,0.f,0.f,0.f}, aL[4] = {0.f,0.f,0.f,0.f}, aR[4] = {0.f,0.f,0.f,0.f};

    auto taprow = [&](int kap, int i0, int i1) {
        int r = ty4 + kap;
        #pragma unroll
        for (int dx = 0; dx < 12; ++dx) {
            uint2 v = tile[c][r][tx + dx];
            float ep = __uint_as_float(v.x << 16);
            float em = __uint_as_float(v.x & 0xffff0000u);
            float cl = __uint_as_float(v.y << 16);
            float cr = __uint_as_float(v.y & 0xffff0000u);
            #pragma unroll
            for (int i = 0; i < 4; ++i) {
                if (i >= i0 && i <= i1) {
                    float t = fminf(emc[i] * ep, epc[i] * em);
                    wg[i] += t;
                    aL[i] = fmaf(t, cl, aL[i]);
                    aR[i] = fmaf(t, cr, aR[i]);
                }
            }
        }
    };

    taprow(0, 0, 0);
    taprow(1, 0, 1);
    taprow(2, 0, 2);
    for (int kap = 3; kap <= 11; ++kap)   // rolled bulk: all 4 outputs eligible
        taprow(kap, 0, 3);
    taprow(12, 1, 3);
    taprow(13, 2, 3);
    taprow(14, 3, 3);

    float vals[6] = {0.f, 0.f, 0.f, 0.f, 0.f, 0.f};
    #pragma unroll
    for (int i = 0; i < 4; ++i) {
        int idx = (gy0 + ty4 + i) * WW + gx0 + tx;
        float g = left[c*HW + idx];
        float aswL   = aL[i] / wg[i];
        float photoL = fabsf(g - rir[c*HW + idx]);
        float sLp = 0.5f * photoL + 0.5f * aswL;
        float aswR   = aR[i] / wg[i];
        float photoR = fabsf(right[c*HW + idx] - ril[c*HW + idx]);
        float sRp = 0.5f * photoR + 0.5f * aswR;
        float pl = pL[idx], pr = pR[idx];
        float mL = (pl > 0.5f) ? 1.f : 0.f;
        float mR = (pr > 0.5f) ? 1.f : 0.f;
        vals[0] += sLp * mL;
        vals[2] += sRp * mR;
        if (c == 0) {   // per-pixel terms counted once
            vals[1] += mL;
            vals[3] += mR;
            vals[4] += log1pf(__expf(1.f - 2.f * pl));
            vals[5] += log1pf(__expf(1.f - 2.f * pr));
        }
    }

    int lane = tid & 63, wave = tid >> 6;
    #pragma unroll
    for (int k = 0; k < 6; ++k) {
        float v = vals[k];
        #pragma unroll
        for (int off = 32; off > 0; off >>= 1) v += __shfl_down(v, off);
        if (lane == 0) red[wave][k] = v;
    }
    __syncthreads();
    if (tid == 0) {
        #pragma unroll
        for (int k = 0; k < 6; ++k) {
            float s = red[0][k] + red[1][k] + red[2][k] + red[3][k] + red[4][k] + red[5][k];
            atomicAdd(&acc[k], s);
        }
    }
}

// ---------------- K4: finalize ----------------

__global__ void k_final(const float* __restrict__ acc, const float* __restrict__ weight,
                        float* __restrict__ out)
{
    float S1 = acc[0], M1 = acc[1], S2 = acc[2], M2 = acc[3], C1 = acc[4], C2 = acc[5];
    float loss_valid = S1 / (3.f * M1 + 1e-6f) + S2 / (3.f * M2 + 1e-6f);
    float loss_invalid = (C1 + C2) * (1.f / (float)HW);
    out[0] = weight[0] * (0.9f * loss_valid + 0.1f * loss_invalid);
}

// ---------------- launch ----------------

extern "C" void kernel_launch(void* const* d_in, const int* in_sizes, int n_in,
                              void* d_out, int out_size, void* d_ws, size_t ws_size,
                              hipStream_t stream)
{
    const float* left  = (const float*)d_in[0];
    const float* right = (const float*)d_in[1];
    const float* dispL = (const float*)d_in[2];
    const float* dispR = (const float*)d_in[3];
    // d_in[4] = dispmap_gt (unused), d_in[5] = brk (unused)
    const float* weight = (const float*)d_in[6];

    float* ws    = (float*)d_ws;
    float* acc   = ws;              // 8 floats (6 used)
    float* rir   = ws + 8;          // 3*HW
    float* ril   = rir + 3*HW;      // 3*HW
    float* pL    = ril + 3*HW;      // HW
    float* pR    = pL + HW;         // HW
    float* costL = pR + HW;         // 3*HW
    float* costR = costL + 3*HW;    // 3*HW

    hipMemsetAsync(acc, 0, 8 * sizeof(float), stream);

    k_resample<<<(HW + 255) / 256, 256, 0, stream>>>(left, right, dispL, dispR, rir, ril, pL, pR);

    dim3 blk2(32, 8);
    dim3 grd2(WW / 32, HH / 8, 2);
    k_lcncost<<<grd2, blk2, 0, stream>>>(left, right, rir, ril, costL, costR);

    dim3 blk3(32, 4, 3);
    dim3 grd3(WW / 32, HH / 16);
    k_asw_reduce<<<grd3, blk3, 0, stream>>>(left, right, rir, ril, costL, costR, pL, pR, acc);

    k_final<<<1, 1, 0, stream>>>(acc, weight, (float*)d_out);
}